// Round 4
// baseline (33.685 us; speedup 1.0000x reference)
//
#include <hip/hip_runtime.h>
#include <math.h>

#define NB 512
#define HW 169
#define NA 5
#define NCH 125
#define BLOCK 256
#define NBLOCKS ((NB * HW) / BLOCK)   // 338
#define REC 8                          // padded per-block record (dwords)
#define SLAB_F4 ((BLOCK * NCH) / 4)    // 8000 float4 per block slab

__global__ __launch_bounds__(BLOCK, 2) void yolo_loss_main(
    const float* __restrict__ P,    // [B][125][169]
    const float* __restrict__ T,    // [B][169][125]
    const float* __restrict__ ANC,  // [5][2]
    float* __restrict__ brec)       // [NBLOCKS][REC]
{
    __shared__ float sT[BLOCK][25];   // compacted gt: [cell][anchor*5 + {conf,x,y,w,h}]

    int t = threadIdx.x;
    int gcell = blockIdx.x * BLOCK + t;
    int b  = gcell / HW;
    int hw = gcell - b * HW;

    // ---- P loads (coalesced: lanes consecutive within 676-B channel planes); issue early
    const float* Pb = P + (size_t)b * NCH * HW + hw;
    float rx[NA], ry[NA], rw[NA], rh[NA];
#pragma unroll
    for (int a = 0; a < NA; ++a) {
        int c0 = a * 25;
        rx[a] = Pb[(c0 + 21) * HW];
        ry[a] = Pb[(c0 + 22) * HW];
        rw[a] = Pb[(c0 + 23) * HW];
        rh[a] = Pb[(c0 + 24) * HW];
    }

    // ---- stream this block's contiguous 128-KB T slab as float4 (perfect coalescing),
    //      compact the needed 25 floats/cell into LDS
    const float4* T4 = (const float4*)T + (size_t)blockIdx.x * SLAB_F4;
#pragma unroll 4
    for (int k = 0; k < 32; ++k) {
        int li = t + k * BLOCK;                  // float4 index within slab
        if (li < SLAB_F4) {
            float4 v = T4[li];
            float vv[4] = {v.x, v.y, v.z, v.w};
            int Lf = li * 4;                     // float offset within slab
#pragma unroll
            for (int i = 0; i < 4; ++i) {
                int c = Lf + i;
                int cell = c / 125;              // local cell 0..255
                int chan = c - cell * 125;
                int a = chan / 25;
                int r = chan - a * 25;
                if (r >= 20) sT[cell][a * 5 + (r - 20)] = vv[i];
            }
        }
    }
    __syncthreads();

    // ---- per-cell compute from LDS (stride-25 reads: coprime with 32 banks)
    float px[NA], py[NA], pw[NA], ph[NA];
    float gx[NA], gy[NA], gw_[NA], gh[NA], gc[NA];
#pragma unroll
    for (int a = 0; a < NA; ++a) {
        gc[a]  = sT[t][a * 5 + 0];
        gx[a]  = sT[t][a * 5 + 1];
        gy[a]  = sT[t][a * 5 + 2];
        gw_[a] = sT[t][a * 5 + 3];
        gh[a]  = sT[t][a * 5 + 4];
        px[a] = 1.0f / (1.0f + expf(-rx[a]));
        py[a] = 1.0f / (1.0f + expf(-ry[a]));
        pw[a] = expf(rw[a]);
        ph[a] = expf(rh[a]);
    }

    float contrib[NA];
    int cmask = 0;
#pragma unroll
    for (int i = 0; i < NA; ++i) {
        float aw = ANC[2 * i], ah = ANC[2 * i + 1];
        float ax1 = px[i] - aw * 0.5f, ax2 = px[i] + aw * 0.5f;
        float ay1 = py[i] - ah * 0.5f, ay2 = py[i] + ah * 0.5f;
        float area_a = (ax2 - ax1) * (ay2 - ay1);
        float best = -1.0f; int bestj = 0;
#pragma unroll
        for (int j = 0; j < NA; ++j) {
            float bx1 = gx[j] - gw_[j] * 0.5f, bx2 = gx[j] + gw_[j] * 0.5f;
            float by1 = gy[j] - gh[j] * 0.5f, by2 = gy[j] + gh[j] * 0.5f;
            float iw = fmaxf(fminf(ax2, bx2) - fmaxf(ax1, bx1), 0.0f);
            float ih = fmaxf(fminf(ay2, by2) - fmaxf(ay1, by1), 0.0f);
            float inter = iw * ih;
            float area_b = (bx2 - bx1) * (by2 - by1);
            float iou = inter / (area_a + area_b - inter + 1e-10f);
            if (iou > best) { best = iou; bestj = j; }   // strict > == jnp.argmax first-max
        }
        cmask |= (1 << bestj);
        float dx = px[i] - gx[i], dy = py[i] - gy[i];
        float dw = pw[i] - gw_[i], dh = ph[i] - gh[i];
        contrib[i] = gc[i] * gc[i] * (dx * dx + dy * dy + dw * dw + dh * dh);
    }

    // ---- wave shuffle reduce -> cross-wave via LDS -> one 32-B record per block
    __shared__ float sred[4][NA];
    __shared__ int smask[4];
    int lane = t & 63, wid = t >> 6;

#pragma unroll
    for (int i = 0; i < NA; ++i) {
        float v = contrib[i];
        for (int off = 32; off; off >>= 1) v += __shfl_down(v, off, 64);
        if (lane == 0) sred[wid][i] = v;
    }
    for (int off = 32; off; off >>= 1) cmask |= __shfl_down(cmask, off, 64);
    if (lane == 0) smask[wid] = cmask;
    __syncthreads();

    if (t == 0) {
        int m = smask[0] | smask[1] | smask[2] | smask[3];
        float* r = brec + blockIdx.x * REC;
#pragma unroll
        for (int i = 0; i < NA; ++i)
            r[i] = sred[0][i] + sred[1][i] + sred[2][i] + sred[3][i];
        ((int*)r)[5] = m;
        ((int*)r)[6] = 0;
        ((int*)r)[7] = 0;
    }
}

__global__ void yolo_loss_final(const float* __restrict__ brec,
                                float* __restrict__ out)
{
    int lane = threadIdx.x;          // one 64-lane wave
    const float4* r4 = (const float4*)brec;
    double s[NA] = {0, 0, 0, 0, 0};
    int m = 0;
    for (int e = lane; e < NBLOCKS; e += 64) {
        float4 lo = r4[e * 2];
        float4 hi = r4[e * 2 + 1];
        s[0] += (double)lo.x; s[1] += (double)lo.y;
        s[2] += (double)lo.z; s[3] += (double)lo.w;
        s[4] += (double)hi.x;
        m |= __float_as_int(hi.y);
    }
#pragma unroll
    for (int i = 0; i < NA; ++i)
        for (int off = 32; off; off >>= 1) s[i] += __shfl_down(s[i], off, 64);
    for (int off = 32; off; off >>= 1) m |= __shfl_down(m, off, 64);

    if (lane == 0) {
        double tot = 0.0;
#pragma unroll
        for (int i = 0; i < NA; ++i)
            if ((m >> i) & 1) tot += s[i];
        out[0] = (float)((5.0 / 512.0) * tot);
    }
}

extern "C" void kernel_launch(void* const* d_in, const int* in_sizes, int n_in,
                              void* d_out, int out_size, void* d_ws, size_t ws_size,
                              hipStream_t stream) {
    const float* P   = (const float*)d_in[0];
    const float* T   = (const float*)d_in[1];
    const float* ANC = (const float*)d_in[2];
    float* out = (float*)d_out;

    float* brec = (float*)d_ws;   // NBLOCKS * REC floats

    yolo_loss_main<<<NBLOCKS, BLOCK, 0, stream>>>(P, T, ANC, brec);
    yolo_loss_final<<<1, 64, 0, stream>>>(brec, out);
}

// Round 5
// 20.858 us; speedup vs baseline: 1.6150x; 1.6150x over previous
//
#include <hip/hip_runtime.h>
#include <math.h>

#define NB 512
#define HW 169
#define NA 5
#define NCH 125
#define BLOCK 256
#define NBLOCKS ((NB * HW) / BLOCK)   // 338
#define REC 8                          // padded per-block record (dwords)

__global__ __launch_bounds__(BLOCK, 1) void yolo_loss_main(
    const float* __restrict__ P,    // [B][125][169] (channel-major)
    const float* __restrict__ T,    // [B][169][125]
    const float* __restrict__ ANC,  // [5][2]
    float* __restrict__ brec)       // [NBLOCKS][REC]
{
    int t = threadIdx.x;
    int idx = blockIdx.x * BLOCK + t;
    int b  = idx / HW;
    int hw = idx - b * HW;

    const float* Pb = P + (size_t)b * NCH * HW + hw;
    const float* Tb = T + ((size_t)b * HW + hw) * NCH;

    // ---- issue ALL 45 independent loads first (T gathers are the long pole: issue first)
    float gx[NA], gy[NA], gw_[NA], gh[NA], gc[NA];
    float rx[NA], ry[NA], rw[NA], rh[NA];
#pragma unroll
    for (int a = 0; a < NA; ++a) {
        int c0 = a * 25;
        gc[a]  = Tb[c0 + 20];
        gx[a]  = Tb[c0 + 21];
        gy[a]  = Tb[c0 + 22];
        gw_[a] = Tb[c0 + 23];
        gh[a]  = Tb[c0 + 24];
    }
#pragma unroll
    for (int a = 0; a < NA; ++a) {
        int c0 = a * 25;
        rx[a] = Pb[(c0 + 21) * HW];
        ry[a] = Pb[(c0 + 22) * HW];
        rw[a] = Pb[(c0 + 23) * HW];
        rh[a] = Pb[(c0 + 24) * HW];
    }
    // keep every load above this line; consumers below -> max loads in flight
    __builtin_amdgcn_sched_barrier(0);

    // ---- transforms
    float px[NA], py[NA], pw[NA], ph[NA];
#pragma unroll
    for (int a = 0; a < NA; ++a) {
        px[a] = 1.0f / (1.0f + expf(-rx[a]));
        py[a] = 1.0f / (1.0f + expf(-ry[a]));
        pw[a] = expf(rw[a]);
        ph[a] = expf(rh[a]);
    }

    float contrib[NA];
    int cmask = 0;
#pragma unroll
    for (int i = 0; i < NA; ++i) {
        float aw = ANC[2 * i], ah = ANC[2 * i + 1];
        float ax1 = px[i] - aw * 0.5f, ax2 = px[i] + aw * 0.5f;
        float ay1 = py[i] - ah * 0.5f, ay2 = py[i] + ah * 0.5f;
        float area_a = (ax2 - ax1) * (ay2 - ay1);
        float best = -1.0f; int bestj = 0;
#pragma unroll
        for (int j = 0; j < NA; ++j) {
            float bx1 = gx[j] - gw_[j] * 0.5f, bx2 = gx[j] + gw_[j] * 0.5f;
            float by1 = gy[j] - gh[j] * 0.5f, by2 = gy[j] + gh[j] * 0.5f;
            float iw = fmaxf(fminf(ax2, bx2) - fmaxf(ax1, bx1), 0.0f);
            float ih = fmaxf(fminf(ay2, by2) - fmaxf(ay1, by1), 0.0f);
            float inter = iw * ih;
            float area_b = (bx2 - bx1) * (by2 - by1);
            float iou = inter / (area_a + area_b - inter + 1e-10f);
            if (iou > best) { best = iou; bestj = j; }   // strict > == jnp.argmax first-max
        }
        cmask |= (1 << bestj);
        float dx = px[i] - gx[i], dy = py[i] - gy[i];
        float dw = pw[i] - gw_[i], dh = ph[i] - gh[i];
        contrib[i] = gc[i] * gc[i] * (dx * dx + dy * dy + dw * dw + dh * dh);
    }

    // ---- wave shuffle reduce -> cross-wave via LDS -> one 32-B record per block
    __shared__ float sred[4][NA];
    __shared__ int smask[4];
    int lane = t & 63, wid = t >> 6;

#pragma unroll
    for (int i = 0; i < NA; ++i) {
        float v = contrib[i];
        for (int off = 32; off; off >>= 1) v += __shfl_down(v, off, 64);
        if (lane == 0) sred[wid][i] = v;
    }
    for (int off = 32; off; off >>= 1) cmask |= __shfl_down(cmask, off, 64);
    if (lane == 0) smask[wid] = cmask;
    __syncthreads();

    if (t == 0) {
        int m = smask[0] | smask[1] | smask[2] | smask[3];
        float* r = brec + blockIdx.x * REC;
#pragma unroll
        for (int i = 0; i < NA; ++i)
            r[i] = sred[0][i] + sred[1][i] + sred[2][i] + sred[3][i];
        ((int*)r)[5] = m;
        ((int*)r)[6] = 0;
        ((int*)r)[7] = 0;
    }
}

__global__ void yolo_loss_final(const float* __restrict__ brec,
                                float* __restrict__ out)
{
    int lane = threadIdx.x;          // one 64-lane wave
    const float4* r4 = (const float4*)brec;
    double s[NA] = {0, 0, 0, 0, 0};
    int m = 0;
    for (int e = lane; e < NBLOCKS; e += 64) {
        float4 lo = r4[e * 2];
        float4 hi = r4[e * 2 + 1];
        s[0] += (double)lo.x; s[1] += (double)lo.y;
        s[2] += (double)lo.z; s[3] += (double)lo.w;
        s[4] += (double)hi.x;
        m |= __float_as_int(hi.y);
    }
#pragma unroll
    for (int i = 0; i < NA; ++i)
        for (int off = 32; off; off >>= 1) s[i] += __shfl_down(s[i], off, 64);
    for (int off = 32; off; off >>= 1) m |= __shfl_down(m, off, 64);

    if (lane == 0) {
        double tot = 0.0;
#pragma unroll
        for (int i = 0; i < NA; ++i)
            if ((m >> i) & 1) tot += s[i];
        out[0] = (float)((5.0 / 512.0) * tot);
    }
}

extern "C" void kernel_launch(void* const* d_in, const int* in_sizes, int n_in,
                              void* d_out, int out_size, void* d_ws, size_t ws_size,
                              hipStream_t stream) {
    const float* P   = (const float*)d_in[0];
    const float* T   = (const float*)d_in[1];
    const float* ANC = (const float*)d_in[2];
    float* out = (float*)d_out;

    float* brec = (float*)d_ws;   // NBLOCKS * REC floats

    yolo_loss_main<<<NBLOCKS, BLOCK, 0, stream>>>(P, T, ANC, brec);
    yolo_loss_final<<<1, 64, 0, stream>>>(brec, out);
}